// Round 4
// baseline (761.583 us; speedup 1.0000x reference)
//
#include <hip/hip_runtime.h>
#include <hip/hip_bf16.h>

// Problem constants (fixed by setup_inputs)
static constexpr int kN = 50000;   // nodes
static constexpr int kR = 1000;    // relations
static constexpr int kT = 400000;  // triples/edges
static constexpr int kD = 256;     // feature dim
static constexpr int kOutD = 768;  // D*(depth+1)

#define EPS_NORM 1e-12f

__device__ __forceinline__ float bf2f(__hip_bfloat16 h) { return __bfloat162float(h); }

// Runtime-dtype-robust loads (flags decided by detect_kernel from the data)
__device__ __forceinline__ float loadF(const void* p, int i, int f32m) {
  return f32m ? ((const float*)p)[i] : bf2f(((const __hip_bfloat16*)p)[i]);
}
__device__ __forceinline__ int loadI(const void* p, int i, int i64m) {
  return i64m ? (int)(((const long long*)p)[i]) : ((const int*)p)[i];
}

// ---------------------------------------------------------------------------
// Sniff input dtypes. flags[0]=1 if floats are f32 (else bf16); flags[1]=1 if
// ints are int64 (else int32). bf16-view of f32 words trips |v|>64 or NaN
// ~50%/elem; int64 values <2^31 have all-zero odd int32 words.
// ---------------------------------------------------------------------------
__global__ void __launch_bounds__(256) detect_kernel(
    const void* __restrict__ feat, const void* __restrict__ adj,
    int* __restrict__ flags) {
  __shared__ int s_f32, s_i64;
  if (threadIdx.x == 0) { s_f32 = 0; s_i64 = 1; }
  __syncthreads();
  const __hip_bfloat16* fb = (const __hip_bfloat16*)feat;
  for (int i = threadIdx.x; i < 4096; i += 256) {
    const float v = bf2f(fb[i]);
    if (!(fabsf(v) <= 64.f)) atomicExch(&s_f32, 1);  // NaN also trips
  }
  const int* ai = (const int*)adj;
  for (int i = threadIdx.x; i < 2048; i += 256) {
    if (ai[2 * i + 1] != 0) atomicExch(&s_i64, 0);
  }
  __syncthreads();
  if (threadIdx.x == 0) { flags[0] = s_f32; flags[1] = s_i64; }
}

// ---------------------------------------------------------------------------
// rel_norm[r] = rel_emb[r] / max(||rel_emb[r]||, eps)
// attL[l*R + r] = rel_norm[r] . attn_kernels[l]   (layer- and x-independent)
// ---------------------------------------------------------------------------
__global__ void __launch_bounds__(256) relnorm_kernel(
    const void* __restrict__ rel_emb, const void* __restrict__ attn_k,
    float* __restrict__ rel_norm, float* __restrict__ attL,
    const int* __restrict__ flags) {
  const int f32m = flags[0];
  const int r = blockIdx.x;
  const int d = threadIdx.x;
  const float v  = loadF(rel_emb, r * kD + d, f32m);
  const float k0 = loadF(attn_k, d, f32m);
  const float k1 = loadF(attn_k, kD + d, f32m);
  float ss = v * v, d0 = v * k0, d1 = v * k1;
#pragma unroll
  for (int off = 32; off > 0; off >>= 1) {
    ss += __shfl_xor(ss, off);
    d0 += __shfl_xor(d0, off);
    d1 += __shfl_xor(d1, off);
  }
  __shared__ float s_ss[4], s_d0[4], s_d1[4];
  const int wave = threadIdx.x >> 6, lane = threadIdx.x & 63;
  if (lane == 0) { s_ss[wave] = ss; s_d0[wave] = d0; s_d1[wave] = d1; }
  __syncthreads();
  const float tss = s_ss[0] + s_ss[1] + s_ss[2] + s_ss[3];
  const float inv = 1.0f / fmaxf(sqrtf(tss), EPS_NORM);
  rel_norm[r * kD + d] = v * inv;
  if (threadIdx.x == 0) {
    attL[r]      = (s_d0[0] + s_d0[1] + s_d0[2] + s_d0[3]) * inv;
    attL[kR + r] = (s_d1[0] + s_d1[1] + s_d1[2] + s_d1[3]) * inv;
  }
}

// out[:, 0:256] = tanh(features)  (f32; this slice doubles as x for layer 0)
__global__ void __launch_bounds__(256) x0_kernel(
    const void* __restrict__ feat, float* __restrict__ out,
    const int* __restrict__ flags) {
  const int f32m = flags[0];
  const int i = blockIdx.x * 256 + threadIdx.x;  // grid covers exactly N*D
  const float v = tanhf(loadF(feat, i, f32m));
  const int n = i >> 8, d = i & 255;
  out[(size_t)n * kOutD + d] = v;
}

// --------------------------- CSR build over dst ----------------------------
__global__ void __launch_bounds__(256) count_kernel(
    const void* __restrict__ adj, int* __restrict__ counts,
    const int* __restrict__ flags) {
  const int t = blockIdx.x * 256 + threadIdx.x;
  if (t >= kT) return;
  atomicAdd(&counts[loadI(adj, t, flags[1])], 1);
}

// Single-block exclusive scan of counts[0..kN) -> offsets, cursor
__global__ void __launch_bounds__(256) scan_kernel(
    const int* __restrict__ counts, int* __restrict__ offsets,
    int* __restrict__ cursor) {
  __shared__ int s_base;
  __shared__ int s_wsum[4];
  const int tid = threadIdx.x, lane = tid & 63, wv = tid >> 6;
  if (tid == 0) s_base = 0;
  __syncthreads();
  for (int base = 0; base < kN; base += 256) {
    const int i = base + tid;
    const int v = (i < kN) ? counts[i] : 0;
    int x = v;  // wave-inclusive scan
#pragma unroll
    for (int d = 1; d < 64; d <<= 1) {
      const int y = __shfl_up(x, d);
      if (lane >= d) x += y;
    }
    if (lane == 63) s_wsum[wv] = x;
    __syncthreads();
    int woff = 0;
    for (int w = 0; w < wv; ++w) woff += s_wsum[w];
    const int excl = s_base + woff + x - v;
    if (i < kN) { offsets[i] = excl; cursor[i] = excl; }
    const int total = s_wsum[0] + s_wsum[1] + s_wsum[2] + s_wsum[3];
    __syncthreads();
    if (tid == 0) s_base += total;
    __syncthreads();
  }
  if (threadIdx.x == 0) offsets[kN] = s_base;  // == kT
}

__global__ void __launch_bounds__(256) fill_kernel(
    const void* __restrict__ adj, int* __restrict__ cursor,
    int* __restrict__ perm, const int* __restrict__ flags) {
  const int t = blockIdx.x * 256 + threadIdx.x;
  if (t >= kT) return;
  const int d = loadI(adj, t, flags[1]);
  perm[atomicAdd(&cursor[d], 1)] = t;
}

// ---------------------------------------------------------------------------
// One block (256 thr = 4 waves) per destination node. Fuses per-edge logits,
// in-block softmax, wave-per-edge gather+reflection+weighted accumulate, and
// tanh + f32 store. No global atomics, no big scratch.
// ---------------------------------------------------------------------------
__global__ void __launch_bounds__(256) layer_kernel(
    const void* __restrict__ adj, const void* __restrict__ rrel,
    const void* __restrict__ r_val,
    const int* __restrict__ offsets, const int* __restrict__ perm,
    const float* __restrict__ xin,  // out + l*kD, row stride kOutD
    const float* __restrict__ rel_norm, const float* __restrict__ attL_l,
    float* __restrict__ out, int col0,
    const int* __restrict__ flags) {
  const int f32m = flags[0], i64m = flags[1];
  const int n = blockIdx.x, tid = threadIdx.x;
  const int lane = tid & 63, wv = tid >> 6;
  const int beg = offsets[n];
  const int cnt = offsets[n + 1] - beg;

  __shared__ float s_red[4];
  __shared__ float s_m, s_s;
  __shared__ float s_acc[4][256];

  if (cnt == 0) {  // no incoming edges: segment_sum = 0, tanh(0) = 0
    out[(size_t)n * kOutD + col0 + tid] = 0.f;
    return;
  }

  // ---- softmax max ----
  float lmax = -1e30f;
  for (int i = tid; i < cnt; i += 256) {
    const int t = perm[beg + i];
    const float rv = loadF(r_val, t, f32m);
    const float s = (rv > 0.f) ? 1.f : ((rv < 0.f) ? -1.f : 0.f);
    lmax = fmaxf(lmax, s * attL_l[loadI(rrel, t, i64m)]);
  }
#pragma unroll
  for (int off = 32; off > 0; off >>= 1) lmax = fmaxf(lmax, __shfl_xor(lmax, off));
  if (lane == 0) s_red[wv] = lmax;
  __syncthreads();
  if (tid == 0) s_m = fmaxf(fmaxf(s_red[0], s_red[1]), fmaxf(s_red[2], s_red[3]));
  __syncthreads();
  const float m = s_m;

  // ---- softmax denominator ----
  float lsum = 0.f;
  for (int i = tid; i < cnt; i += 256) {
    const int t = perm[beg + i];
    const float rv = loadF(r_val, t, f32m);
    const float s = (rv > 0.f) ? 1.f : ((rv < 0.f) ? -1.f : 0.f);
    lsum += __expf(s * attL_l[loadI(rrel, t, i64m)] - m);
  }
#pragma unroll
  for (int off = 32; off > 0; off >>= 1) lsum += __shfl_xor(lsum, off);
  __syncthreads();  // s_red reuse
  if (lane == 0) s_red[wv] = lsum;
  __syncthreads();
  if (tid == 0) s_s = s_red[0] + s_red[1] + s_red[2] + s_red[3];
  __syncthreads();
  const float inv_s = 1.f / s_s;

  // ---- weighted reflected-neighbor accumulation: wave per edge ----
  float a0 = 0.f, a1 = 0.f, a2 = 0.f, a3 = 0.f;
  for (int e = wv; e < cnt; e += 4) {
    const int t = perm[beg + e];
    const float rv = loadF(r_val, t, f32m);
    const float sgn = (rv > 0.f) ? 1.f : ((rv < 0.f) ? -1.f : 0.f);
    const float s2 = (rv != 0.f) ? 1.f : 0.f;
    const int r  = loadI(rrel, t, i64m);
    const int sn = loadI(adj, kT + t, i64m);  // src
    const float w = __expf(sgn * attL_l[r] - m) * inv_s;

    const float4 xv = ((const float4*)(xin + (size_t)sn * kOutD))[lane];
    const float4 rn = ((const float4*)(rel_norm + (size_t)r * kD))[lane];

    float dot = xv.x * rn.x + xv.y * rn.y + xv.z * rn.z + xv.w * rn.w;
#pragma unroll
    for (int off = 32; off > 0; off >>= 1) dot += __shfl_xor(dot, off);

    const float c = 2.f * s2 * dot * w;
    a0 += xv.x * w - c * rn.x;
    a1 += xv.y * w - c * rn.y;
    a2 += xv.z * w - c * rn.z;
    a3 += xv.w * w - c * rn.w;
  }
  s_acc[wv][4 * lane + 0] = a0;
  s_acc[wv][4 * lane + 1] = a1;
  s_acc[wv][4 * lane + 2] = a2;
  s_acc[wv][4 * lane + 3] = a3;
  __syncthreads();
  const float tot = s_acc[0][tid] + s_acc[1][tid] + s_acc[2][tid] + s_acc[3][tid];
  out[(size_t)n * kOutD + col0 + tid] = tanhf(tot);
}

extern "C" void kernel_launch(void* const* d_in, const int* in_sizes, int n_in,
                              void* d_out, int out_size, void* d_ws, size_t ws_size,
                              hipStream_t stream) {
  const void* features = d_in[0];  // [N,D]   f32 (detected, hedged)
  const void* rel_emb  = d_in[1];  // [R,D]
  const void* attn_k   = d_in[2];  // [depth,D]
  const void* r_val    = d_in[3];  // [T]
  const void* adj      = d_in[4];  // [2,T]   int32 (detected, hedged)
  // d_in[5] = r_index_tri == arange(T): its segment_sum is an identity gather.
  const void* rrel     = d_in[6];  // [T]
  float* out           = (float*)d_out;  // [N, 768] float32

  // Workspace layout — total ~3.25 MB.
  char* ws = (char*)d_ws;
  int*   flags    = (int*)(ws + 0);          // 2 ints
  float* attL     = (float*)(ws + 4096);     // 2*R fp32 = 8 KB
  int*   counts   = (int*)(ws + 16384);      // N ints   = 200 KB
  int*   offsets  = (int*)(ws + 217088);     // N+1 ints = 200 KB
  int*   cursor   = (int*)(ws + 417792);     // N ints   = 200 KB
  int*   perm     = (int*)(ws + 618496);     // T ints   = 1.6 MB
  float* rel_norm = (float*)(ws + 2219008);  // R*D fp32 = 1.0 MB  (ends ~3.25 MB)

  const int tb = (kT + 255) / 256;

  detect_kernel<<<1, 256, 0, stream>>>(features, adj, flags);
  relnorm_kernel<<<kR, 256, 0, stream>>>(rel_emb, attn_k, rel_norm, attL, flags);
  x0_kernel<<<kN, 256, 0, stream>>>(features, out, flags);

  // CSR over dst (adj constant across layers)
  hipMemsetAsync(counts, 0, (size_t)kN * 4, stream);
  count_kernel<<<tb, 256, 0, stream>>>(adj, counts, flags);
  scan_kernel<<<1, 256, 0, stream>>>(counts, offsets, cursor);
  fill_kernel<<<tb, 256, 0, stream>>>(adj, cursor, perm, flags);

  for (int l = 0; l < 2; ++l) {
    layer_kernel<<<kN, 256, 0, stream>>>(adj, rrel, r_val, offsets, perm,
                                         out + l * kD, rel_norm, attL + l * kR,
                                         out, (l + 1) * kD, flags);
  }
}

// Round 5
// 426.169 us; speedup vs baseline: 1.7870x; 1.7870x over previous
//
#include <hip/hip_runtime.h>
#include <hip/hip_bf16.h>

// Problem constants (fixed by setup_inputs)
static constexpr int kN = 50000;   // nodes
static constexpr int kR = 1000;    // relations
static constexpr int kT = 400000;  // triples/edges
static constexpr int kD = 256;     // feature dim
static constexpr int kOutD = 768;  // D*(depth+1)
static constexpr int kNB = (kN + 255) / 256;  // 196 scan blocks

#define EPS_NORM 1e-12f

__device__ __forceinline__ float bf2f(__hip_bfloat16 h) { return __bfloat162float(h); }

// Runtime-dtype-robust loads (flags decided by detect_kernel from the data)
__device__ __forceinline__ float loadF(const void* p, int i, int f32m) {
  return f32m ? ((const float*)p)[i] : bf2f(((const __hip_bfloat16*)p)[i]);
}
__device__ __forceinline__ int loadI(const void* p, int i, int i64m) {
  return i64m ? (int)(((const long long*)p)[i]) : ((const int*)p)[i];
}

// ---------------------------------------------------------------------------
// Sniff input dtypes. flags[0]=1 if floats are f32 (else bf16); flags[1]=1 if
// ints are int64 (else int32).
// ---------------------------------------------------------------------------
__global__ void __launch_bounds__(256) detect_kernel(
    const void* __restrict__ feat, const void* __restrict__ adj,
    int* __restrict__ flags) {
  __shared__ int s_f32, s_i64;
  if (threadIdx.x == 0) { s_f32 = 0; s_i64 = 1; }
  __syncthreads();
  const __hip_bfloat16* fb = (const __hip_bfloat16*)feat;
  for (int i = threadIdx.x; i < 4096; i += 256) {
    const float v = bf2f(fb[i]);
    if (!(fabsf(v) <= 64.f)) atomicExch(&s_f32, 1);  // NaN also trips
  }
  const int* ai = (const int*)adj;
  for (int i = threadIdx.x; i < 2048; i += 256) {
    if (ai[2 * i + 1] != 0) atomicExch(&s_i64, 0);
  }
  __syncthreads();
  if (threadIdx.x == 0) { flags[0] = s_f32; flags[1] = s_i64; }
}

// ---------------------------------------------------------------------------
// rel_norm[r] = rel_emb[r] / max(||rel_emb[r]||, eps)
// attL[l*R + r] = rel_norm[r] . attn_kernels[l]
// ---------------------------------------------------------------------------
__global__ void __launch_bounds__(256) relnorm_kernel(
    const void* __restrict__ rel_emb, const void* __restrict__ attn_k,
    float* __restrict__ rel_norm, float* __restrict__ attL,
    const int* __restrict__ flags) {
  const int f32m = flags[0];
  const int r = blockIdx.x;
  const int d = threadIdx.x;
  const float v  = loadF(rel_emb, r * kD + d, f32m);
  const float k0 = loadF(attn_k, d, f32m);
  const float k1 = loadF(attn_k, kD + d, f32m);
  float ss = v * v, d0 = v * k0, d1 = v * k1;
#pragma unroll
  for (int off = 32; off > 0; off >>= 1) {
    ss += __shfl_xor(ss, off);
    d0 += __shfl_xor(d0, off);
    d1 += __shfl_xor(d1, off);
  }
  __shared__ float s_ss[4], s_d0[4], s_d1[4];
  const int wave = threadIdx.x >> 6, lane = threadIdx.x & 63;
  if (lane == 0) { s_ss[wave] = ss; s_d0[wave] = d0; s_d1[wave] = d1; }
  __syncthreads();
  const float tss = s_ss[0] + s_ss[1] + s_ss[2] + s_ss[3];
  const float inv = 1.0f / fmaxf(sqrtf(tss), EPS_NORM);
  rel_norm[r * kD + d] = v * inv;
  if (threadIdx.x == 0) {
    attL[r]      = (s_d0[0] + s_d0[1] + s_d0[2] + s_d0[3]) * inv;
    attL[kR + r] = (s_d1[0] + s_d1[1] + s_d1[2] + s_d1[3]) * inv;
  }
}

// out[:, 0:256] = tanh(features), float4 per thread
__global__ void __launch_bounds__(256) x0_kernel(
    const void* __restrict__ feat, float* __restrict__ out,
    const int* __restrict__ flags) {
  const int f32m = flags[0];
  const int i4 = (blockIdx.x * 256 + threadIdx.x) * 4;  // grid covers N*D/4
  float v0, v1, v2, v3;
  if (f32m) {
    const float4 f = ((const float4*)feat)[i4 >> 2];
    v0 = f.x; v1 = f.y; v2 = f.z; v3 = f.w;
  } else {
    union { ushort4 u; __hip_bfloat16 h[4]; } xu;
    xu.u = ((const ushort4*)feat)[i4 >> 2];
    v0 = bf2f(xu.h[0]); v1 = bf2f(xu.h[1]); v2 = bf2f(xu.h[2]); v3 = bf2f(xu.h[3]);
  }
  const int n = i4 >> 8, d = i4 & 255;
  float4 o; o.x = tanhf(v0); o.y = tanhf(v1); o.z = tanhf(v2); o.w = tanhf(v3);
  *(float4*)(out + (size_t)n * kOutD + d) = o;
}

// --------------------------- CSR build over dst ----------------------------
__global__ void __launch_bounds__(256) count_kernel(
    const void* __restrict__ adj, int* __restrict__ counts,
    const int* __restrict__ flags) {
  const int t = blockIdx.x * 256 + threadIdx.x;
  if (t >= kT) return;
  atomicAdd(&counts[loadI(adj, t, flags[1])], 1);
}

// Per-block sums of counts -> partials[kNB]
__global__ void __launch_bounds__(256) psum_kernel(
    const int* __restrict__ counts, int* __restrict__ partials) {
  const int i = blockIdx.x * 256 + threadIdx.x;
  int v = (i < kN) ? counts[i] : 0;
#pragma unroll
  for (int off = 32; off > 0; off >>= 1) v += __shfl_xor(v, off);
  __shared__ int sw[4];
  const int lane = threadIdx.x & 63, wv = threadIdx.x >> 6;
  if (lane == 0) sw[wv] = v;
  __syncthreads();
  if (threadIdx.x == 0) partials[blockIdx.x] = sw[0] + sw[1] + sw[2] + sw[3];
}

// Exclusive scan of partials[kNB] in one block (kNB=196 <= 256)
__global__ void __launch_bounds__(256) pscan_kernel(int* __restrict__ partials) {
  const int tid = threadIdx.x, lane = tid & 63, wv = tid >> 6;
  const int v = (tid < kNB) ? partials[tid] : 0;
  int x = v;
#pragma unroll
  for (int d = 1; d < 64; d <<= 1) {
    const int y = __shfl_up(x, d);
    if (lane >= d) x += y;
  }
  __shared__ int sw[4];
  if (lane == 63) sw[wv] = x;
  __syncthreads();
  int woff = 0;
  for (int w = 0; w < wv; ++w) woff += sw[w];
  if (tid < kNB) partials[tid] = woff + x - v;  // exclusive prefix
}

// offsets[i] = partials[blk] + in-block exclusive scan; cursor := offsets
__global__ void __launch_bounds__(256) offs_kernel(
    const int* __restrict__ counts, const int* __restrict__ partials,
    int* __restrict__ offsets, int* __restrict__ cursor) {
  const int i = blockIdx.x * 256 + threadIdx.x;
  const int lane = threadIdx.x & 63, wv = threadIdx.x >> 6;
  const int v = (i < kN) ? counts[i] : 0;
  int x = v;
#pragma unroll
  for (int d = 1; d < 64; d <<= 1) {
    const int y = __shfl_up(x, d);
    if (lane >= d) x += y;
  }
  __shared__ int sw[4];
  if (lane == 63) sw[wv] = x;
  __syncthreads();
  int woff = 0;
  for (int w = 0; w < wv; ++w) woff += sw[w];
  const int excl = partials[blockIdx.x] + woff + x - v;
  if (i < kN) { offsets[i] = excl; cursor[i] = excl; }
  if (i == 0) offsets[kN] = kT;
}

__global__ void __launch_bounds__(256) fill_kernel(
    const void* __restrict__ adj, int* __restrict__ cursor,
    int* __restrict__ perm, const int* __restrict__ flags) {
  const int t = blockIdx.x * 256 + threadIdx.x;
  if (t >= kT) return;
  const int d = loadI(adj, t, flags[1]);
  perm[atomicAdd(&cursor[d], 1)] = t;
}

// ---------------------------------------------------------------------------
// ONE WAVE PER NODE (4 nodes per 256-thread block). No LDS, no barriers.
// Fast path cnt<=64: lane-parallel logits, butterfly max/sum, then per-edge
// gather with metadata broadcast via shuffles. Lane handles dims 4*lane..+3.
// ---------------------------------------------------------------------------
__global__ void __launch_bounds__(256) layer_kernel(
    const void* __restrict__ adj, const void* __restrict__ rrel,
    const void* __restrict__ r_val,
    const int* __restrict__ offsets, const int* __restrict__ perm,
    const float* __restrict__ xin,  // out + l*kD, row stride kOutD
    const float* __restrict__ rel_norm, const float* __restrict__ attL_l,
    float* __restrict__ out, int col0,
    const int* __restrict__ flags) {
  const int f32m = flags[0], i64m = flags[1];
  const int lane = threadIdx.x & 63;
  const int n = blockIdx.x * 4 + (threadIdx.x >> 6);  // grid*4 == kN exactly
  const int beg = offsets[n];
  const int cnt = offsets[n + 1] - beg;
  float4 acc = make_float4(0.f, 0.f, 0.f, 0.f);
  float* orow = out + (size_t)n * kOutD + col0;

  if (cnt == 0) { *(float4*)(orow + lane * 4) = acc; return; }

  if (cnt <= 64) {
    // lane-parallel edge metadata + logits
    int sn_l = 0, r_l = 0;
    float logit = -1e30f, s2_l = 0.f;
    if (lane < cnt) {
      const int t = perm[beg + lane];
      const float rv = loadF(r_val, t, f32m);
      r_l  = loadI(rrel, t, i64m);
      sn_l = loadI(adj, kT + t, i64m);
      const float sgn = (rv > 0.f) ? 1.f : ((rv < 0.f) ? -1.f : 0.f);
      logit = sgn * attL_l[r_l];
      s2_l = (rv != 0.f) ? 1.f : 0.f;
    }
    float m = logit;
#pragma unroll
    for (int off = 32; off > 0; off >>= 1) m = fmaxf(m, __shfl_xor(m, off));
    const float e = (lane < cnt) ? __expf(logit - m) : 0.f;
    float s = e;
#pragma unroll
    for (int off = 32; off > 0; off >>= 1) s += __shfl_xor(s, off);
    const float w_l = e / s;

    for (int k = 0; k < cnt; ++k) {
      const int sn   = __shfl(sn_l, k);
      const int r    = __shfl(r_l, k);
      const float w  = __shfl(w_l, k);
      const float s2 = __shfl(s2_l, k);
      const float4 xv = *(const float4*)(xin + (size_t)sn * kOutD + lane * 4);
      const float4 rn = *(const float4*)(rel_norm + (size_t)r * kD + lane * 4);
      float dot = xv.x * rn.x + xv.y * rn.y + xv.z * rn.z + xv.w * rn.w;
#pragma unroll
      for (int off = 32; off > 0; off >>= 1) dot += __shfl_xor(dot, off);
      const float c = 2.f * s2 * dot * w;
      acc.x += xv.x * w - c * rn.x;
      acc.y += xv.y * w - c * rn.y;
      acc.z += xv.z * w - c * rn.z;
      acc.w += xv.w * w - c * rn.w;
    }
  } else {
    // generic chunked path (cnt > 64; vanishingly rare at avg degree 8)
    float lm = -1e30f;
    for (int i = lane; i < cnt; i += 64) {
      const int t = perm[beg + i];
      const float rv = loadF(r_val, t, f32m);
      const float sgn = (rv > 0.f) ? 1.f : ((rv < 0.f) ? -1.f : 0.f);
      lm = fmaxf(lm, sgn * attL_l[loadI(rrel, t, i64m)]);
    }
#pragma unroll
    for (int off = 32; off > 0; off >>= 1) lm = fmaxf(lm, __shfl_xor(lm, off));
    float ls = 0.f;
    for (int i = lane; i < cnt; i += 64) {
      const int t = perm[beg + i];
      const float rv = loadF(r_val, t, f32m);
      const float sgn = (rv > 0.f) ? 1.f : ((rv < 0.f) ? -1.f : 0.f);
      ls += __expf(sgn * attL_l[loadI(rrel, t, i64m)] - lm);
    }
#pragma unroll
    for (int off = 32; off > 0; off >>= 1) ls += __shfl_xor(ls, off);
    const float inv_s = 1.f / ls;

    for (int base = 0; base < cnt; base += 64) {
      const int nIn = min(64, cnt - base);
      int sn_l = 0, r_l = 0;
      float w_l = 0.f, s2_l = 0.f;
      if (lane < nIn) {
        const int t = perm[beg + base + lane];
        const float rv = loadF(r_val, t, f32m);
        r_l  = loadI(rrel, t, i64m);
        sn_l = loadI(adj, kT + t, i64m);
        const float sgn = (rv > 0.f) ? 1.f : ((rv < 0.f) ? -1.f : 0.f);
        w_l = __expf(sgn * attL_l[r_l] - lm) * inv_s;
        s2_l = (rv != 0.f) ? 1.f : 0.f;
      }
      for (int k = 0; k < nIn; ++k) {
        const int sn   = __shfl(sn_l, k);
        const int r    = __shfl(r_l, k);
        const float w  = __shfl(w_l, k);
        const float s2 = __shfl(s2_l, k);
        const float4 xv = *(const float4*)(xin + (size_t)sn * kOutD + lane * 4);
        const float4 rn = *(const float4*)(rel_norm + (size_t)r * kD + lane * 4);
        float dot = xv.x * rn.x + xv.y * rn.y + xv.z * rn.z + xv.w * rn.w;
#pragma unroll
        for (int off = 32; off > 0; off >>= 1) dot += __shfl_xor(dot, off);
        const float c = 2.f * s2 * dot * w;
        acc.x += xv.x * w - c * rn.x;
        acc.y += xv.y * w - c * rn.y;
        acc.z += xv.z * w - c * rn.z;
        acc.w += xv.w * w - c * rn.w;
      }
    }
  }

  acc.x = tanhf(acc.x); acc.y = tanhf(acc.y);
  acc.z = tanhf(acc.z); acc.w = tanhf(acc.w);
  *(float4*)(orow + lane * 4) = acc;
}

extern "C" void kernel_launch(void* const* d_in, const int* in_sizes, int n_in,
                              void* d_out, int out_size, void* d_ws, size_t ws_size,
                              hipStream_t stream) {
  const void* features = d_in[0];  // [N,D]   f32 (detected, hedged)
  const void* rel_emb  = d_in[1];  // [R,D]
  const void* attn_k   = d_in[2];  // [depth,D]
  const void* r_val    = d_in[3];  // [T]
  const void* adj      = d_in[4];  // [2,T]   int32 (detected, hedged)
  // d_in[5] = r_index_tri == arange(T): its segment_sum is an identity gather.
  const void* rrel     = d_in[6];  // [T]
  float* out           = (float*)d_out;  // [N, 768] float32

  // Workspace layout — total ~3.25 MB (proven safe in round 4).
  char* ws = (char*)d_ws;
  int*   flags    = (int*)(ws + 0);          // 2 ints
  float* attL     = (float*)(ws + 4096);     // 2*R fp32 = 8 KB
  int*   partials = (int*)(ws + 12288);      // kNB ints
  int*   counts   = (int*)(ws + 16384);      // N ints   = 200 KB
  int*   offsets  = (int*)(ws + 217088);     // N+1 ints = 200 KB
  int*   cursor   = (int*)(ws + 417792);     // N ints   = 200 KB
  int*   perm     = (int*)(ws + 618496);     // T ints   = 1.6 MB
  float* rel_norm = (float*)(ws + 2219008);  // R*D fp32 = 1.0 MB

  const int tb = (kT + 255) / 256;

  detect_kernel<<<1, 256, 0, stream>>>(features, adj, flags);
  relnorm_kernel<<<kR, 256, 0, stream>>>(rel_emb, attn_k, rel_norm, attL, flags);
  x0_kernel<<<kN * kD / 1024, 256, 0, stream>>>(features, out, flags);

  // CSR over dst (adj constant across layers)
  hipMemsetAsync(counts, 0, (size_t)kN * 4, stream);
  count_kernel<<<tb, 256, 0, stream>>>(adj, counts, flags);
  psum_kernel<<<kNB, 256, 0, stream>>>(counts, partials);
  pscan_kernel<<<1, 256, 0, stream>>>(partials);
  offs_kernel<<<kNB, 256, 0, stream>>>(counts, partials, offsets, cursor);
  fill_kernel<<<tb, 256, 0, stream>>>(adj, cursor, perm, flags);

  for (int l = 0; l < 2; ++l) {
    layer_kernel<<<kN / 4, 256, 0, stream>>>(adj, rrel, r_val, offsets, perm,
                                             out + l * kD, rel_norm, attL + l * kR,
                                             out, (l + 1) * kD, flags);
  }
}